// Round 8
// baseline (72.414 us; speedup 1.0000x reference)
//
#include <hip/hip_runtime.h>

// ButterflyRotation: 12 butterfly layers over rows of 4096 fp32.
// R8: 4 rows/block (2 pairs), BLOCK=512, 64 KiB LDS, radix-16 x 3 phases,
// pairs interleaved within each phase (ILP: pairB LDS ops overlap pairA
// math). u=t&255 is in-row position (R5's verified mappings); h=t>>8 picks
// the row within each pair. 3 lgkm-only barriers per block. Grid 2048,
// dispatch-ordered streaming (no persistence -- R6 lesson).
//   P1: e = 16u+k                   -> layers 0-3   (b128 LDS)
//   P2: e = 256(u&15)+16m+(u>>4)    -> layers 4-7   (b32, 2-way free)
//   P3: e = u+256m                  -> layers 8-11  (b32, 2-way free)

#define DIM    4096
#define LAYERS 12
#define BATCH  8192
#define NANG   2048
#define BLOCK  512
#define ROWS   4

typedef unsigned int u32;

// lgkm-only barrier: global loads stay in flight across it
#define BAR() do {                                             \
    asm volatile("s_waitcnt lgkmcnt(0)" ::: "memory");         \
    __builtin_amdgcn_sched_barrier(0);                         \
    __builtin_amdgcn_s_barrier();                              \
} while (0)

// quad-level swizzle (involution: only bits 0-2 change)
__device__ __forceinline__ int swzQ(int Q) {
    return Q ^ ((Q >> 3) & 7) ^ ((Q >> 6) & 7);
}
// element -> swizzled LDS slot (within one row)
__device__ __forceinline__ int perm(int e) {
    return (swzQ(e >> 2) << 2) | (e & 3);
}
// butterfly sub-index for left element m at local level jj (stride 2^jj)
__device__ __forceinline__ constexpr int inner_idx(int m, int jj) {
    return ((m >> (jj + 1)) << jj) + (m & ((1 << jj) - 1));
}

__device__ __forceinline__ void rot(float& xl, float& xr, float c, float s) {
    float nl = fmaf(s, xr, c * xl);
    float nr = fmaf(-s, xl, c * xr);
    xl = nl; xr = nr;
}

// Transposed cos/sin table, keyed to u in [0,256) (same as R5):
//  region A (f4 [0,4096)):     layer l:   angles 8u+2k2(+1)
//  region B (f4 [4096,8192)):  layer 4+j: angles 128(u&15)+(u>>4)+16*(2k2(+1))
//  region C (f4 [8192,12288)): layer 8+j: angles u+256*(2k2(+1))
__global__ void __launch_bounds__(256) cs_kernel(const float* __restrict__ angles,
                                                 float2* __restrict__ T, int n) {
    int i = blockIdx.x * blockDim.x + threadIdx.x;
    if (i >= n) return;
    float a = angles[i];
    float c = cosf(a), s = sinf(a);
    int l = i >> 11, aa = i & 2047;
    int f4, half;
    if (l < 4) {
        int u = aa >> 3, k = aa & 7;
        f4 = (l * 4 + (k >> 1)) * 256 + u; half = k & 1;
    } else if (l < 8) {
        int hi = aa >> 7, k = (aa >> 4) & 7, lo = aa & 15;
        int u = hi + (lo << 4);
        f4 = 4096 + ((l - 4) * 4 + (k >> 1)) * 256 + u; half = k & 1;
    } else {
        int k = aa >> 8, u = aa & 255;
        f4 = 8192 + ((l - 8) * 4 + (k >> 1)) * 256 + u; half = k & 1;
    }
    T[f4 * 2 + half] = make_float2(c, s);
}

// apply one layer's rotations to both pairs' 16-element registers
#define LAYER_ROTS(A0, A1, A2, A3, st, va, vb)                             \
    _Pragma("unroll")                                                      \
    for (int m = 0; m < 16; ++m) {                                         \
        if (!(m & (st))) {                                                 \
            const int ii = inner_idx(m, LVL);                              \
            const float4 Ax = (ii >> 1) == 0 ? A0 : (ii >> 1) == 1 ? A1    \
                             : (ii >> 1) == 2 ? A2 : A3;                   \
            const float c = (ii & 1) ? Ax.z : Ax.x;                        \
            const float s = (ii & 1) ? Ax.w : Ax.y;                        \
            rot(va[m], va[m + (st)], c, s);                                \
            rot(vb[m], vb[m + (st)], c, s);                                \
        }                                                                  \
    }

__global__ void __launch_bounds__(BLOCK, 4)
butterfly_kernel(const float* __restrict__ x, const float4* __restrict__ T4,
                 float* __restrict__ out) {
    __shared__ float lds[ROWS * DIM];       // 64 KiB: 4 rows
    const int t = threadIdx.x;
    const int u = t & 255, h = t >> 8;      // in-row position, row-within-pair
    const int wave = t >> 6, lane = t & 63;
    const long row0 = (long)blockIdx.x * ROWS;
    const int bA = h * DIM;                 // LDS base: pairA row h
    const int bB = (2 + h) * DIM;           // LDS base: pairB row h

    // ---- stage all 4 rows: linear LDS dest, swizzled global src ----
    #pragma unroll
    for (int j = 0; j < 8; ++j) {
        const int dqb = wave * 512 + j * 64;           // wave-uniform dest quad
        const int row = dqb >> 10;
        const int g = swzQ((dqb & 1023) + lane);       // logical quad in row
        __builtin_amdgcn_global_load_lds(
            (const __attribute__((address_space(1))) u32*)(x + (row0 + row) * DIM + 4 * g),
            (__attribute__((address_space(3))) u32*)(lds + 4 * dqb),
            16, 0, 0);
    }
    asm volatile("s_waitcnt vmcnt(0)" ::: "memory");
    __builtin_amdgcn_sched_barrier(0);
    __builtin_amdgcn_s_barrier();

    float va[16], vb[16];

    // ================= P1: e = 16u + k, layers 0-3 (b128) =================
    {
        int pa[4];
        #pragma unroll
        for (int q = 0; q < 4; ++q) {
            pa[q] = 4 * swzQ(4 * u + q);
            float4 xa = *(const float4*)(lds + bA + pa[q]);
            float4 xb = *(const float4*)(lds + bB + pa[q]);
            va[4*q+0] = xa.x; va[4*q+1] = xa.y; va[4*q+2] = xa.z; va[4*q+3] = xa.w;
            vb[4*q+0] = xb.x; vb[4*q+1] = xb.y; vb[4*q+2] = xb.z; vb[4*q+3] = xb.w;
        }
        #pragma unroll
        for (int l = 0; l < 4; ++l) {
            const float4 A0 = T4[(l*4+0)*256 + u], A1 = T4[(l*4+1)*256 + u],
                         A2 = T4[(l*4+2)*256 + u], A3 = T4[(l*4+3)*256 + u];
            #define LVL l
            LAYER_ROTS(A0, A1, A2, A3, 1 << l, va, vb)
            #undef LVL
        }
        #pragma unroll
        for (int q = 0; q < 4; ++q) {
            *(float4*)(lds + bA + pa[q]) = make_float4(va[4*q], va[4*q+1], va[4*q+2], va[4*q+3]);
            *(float4*)(lds + bB + pa[q]) = make_float4(vb[4*q], vb[4*q+1], vb[4*q+2], vb[4*q+3]);
        }
    }
    BAR();

    // ================= P2: e = 256*hi + 16m + lo, layers 4-7 =================
    {
        const int hi = u & 15, lo = u >> 4;
        int ps[16];
        #pragma unroll
        for (int m = 0; m < 16; ++m) {
            ps[m] = perm((hi << 8) + (m << 4) + lo);
            va[m] = lds[bA + ps[m]];
            vb[m] = lds[bB + ps[m]];
        }
        #pragma unroll
        for (int j = 0; j < 4; ++j) {
            const float4 A0 = T4[4096 + (j*4+0)*256 + u], A1 = T4[4096 + (j*4+1)*256 + u],
                         A2 = T4[4096 + (j*4+2)*256 + u], A3 = T4[4096 + (j*4+3)*256 + u];
            #define LVL j
            LAYER_ROTS(A0, A1, A2, A3, 1 << j, va, vb)
            #undef LVL
        }
        #pragma unroll
        for (int m = 0; m < 16; ++m) {
            lds[bA + ps[m]] = va[m];
            lds[bB + ps[m]] = vb[m];
        }
    }
    BAR();

    // ================= P3: e = u + 256m, layers 8-11; store =================
    {
        #pragma unroll
        for (int m = 0; m < 16; ++m) {
            const int p = perm(u + (m << 8));
            va[m] = lds[bA + p];
            vb[m] = lds[bB + p];
        }
        #pragma unroll
        for (int j = 0; j < 4; ++j) {
            const float4 A0 = T4[8192 + (j*4+0)*256 + u], A1 = T4[8192 + (j*4+1)*256 + u],
                         A2 = T4[8192 + (j*4+2)*256 + u], A3 = T4[8192 + (j*4+3)*256 + u];
            #define LVL j
            LAYER_ROTS(A0, A1, A2, A3, 1 << j, va, vb)
            #undef LVL
        }
        float* oA = out + (row0 + h) * DIM + u;
        float* oB = out + (row0 + 2 + h) * DIM + u;
        #pragma unroll
        for (int m = 0; m < 16; ++m) {
            oA[m << 8] = va[m];
            oB[m << 8] = vb[m];
        }
    }
}

extern "C" void kernel_launch(void* const* d_in, const int* in_sizes, int n_in,
                              void* d_out, int out_size, void* d_ws, size_t ws_size,
                              hipStream_t stream) {
    (void)in_sizes; (void)n_in; (void)out_size; (void)ws_size;
    const float* x      = (const float*)d_in[0];
    const float* angles = (const float*)d_in[1];
    float* out = (float*)d_out;

    const int n = LAYERS * NANG;                    // 24576 angles, 192 KiB table
    cs_kernel<<<(n + 255) / 256, 256, 0, stream>>>(angles, (float2*)d_ws, n);
    butterfly_kernel<<<BATCH / ROWS, BLOCK, 0, stream>>>(x, (const float4*)d_ws, out);
}

// Round 9
// 60.987 us; speedup vs baseline: 1.1874x; 1.1874x over previous
//
#include <hip/hip_runtime.h>

// ButterflyRotation: 12 butterfly layers over rows of 4096 fp32.
// R9: R7 skeleton (BLOCK=512, 2 rows, 32 KiB LDS, radix-8 x 4 phases,
// grid 4096 dispatch-ordered) with:
//  - rows packed as float2 in lane + interleaved LDS buf[e]={r0[e],r1[e]}
//    -> ds_*_b64 ops (halves LDS op count + addr math), v_pk_fma_f32 math
//  - P1 reads x directly from global (e=8t+k contiguous) -> staging
//    round-trip + its barrier deleted; 3 lgkm-only barriers total
//   P1: e = 8t+m                    -> layers 0-2
//   P2: e = 64(t>>3)+8m+(t&7)       -> layers 3-5
//   P3: e = 512(t>>6)+64m+(t&63)    -> layers 6-8
//   P4: e = t+512m                  -> layers 9-11

#define DIM    4096
#define LAYERS 12
#define BATCH  8192
#define NANG   2048
#define BLOCK  512

typedef unsigned int u32;
typedef float v2f __attribute__((ext_vector_type(2)));

// lgkm-only barrier: global loads stay in flight across it
#define BAR() do {                                             \
    asm volatile("s_waitcnt lgkmcnt(0)" ::: "memory");         \
    __builtin_amdgcn_sched_barrier(0);                         \
    __builtin_amdgcn_s_barrier();                              \
} while (0)

// quad-level swizzle (involution: only bits 0-2 change)
__device__ __forceinline__ int swzQ(int Q) {
    return Q ^ ((Q >> 3) & 7) ^ ((Q >> 6) & 7);
}
// element -> interleaved 8B-unit slot (quad swizzle in packed space)
__device__ __forceinline__ int uslot(int e) {
    return 2 * swzQ(e >> 1) + (e & 1);
}
// butterfly sub-index for left element m at local level jj (stride 2^jj)
__device__ __forceinline__ constexpr int inner_idx(int m, int jj) {
    return ((m >> (jj + 1)) << jj) + (m & ((1 << jj) - 1));
}

// packed rotation on both rows at once (v_pk_fma_f32 candidates)
__device__ __forceinline__ void rot2(v2f& xl, v2f& xr, float c, float s) {
    v2f nl = c * xl + s * xr;
    v2f nr = c * xr - s * xl;
    xl = nl; xr = nr;
}

// Transposed table (identical to R7): 4 regions x 3 layers x 2 k2 x 512
// threads of float4; each float4 = (c,s) for ii=2k2, 2k2+1. 192 KiB.
__global__ void __launch_bounds__(256) cs_kernel(const float* __restrict__ angles,
                                                 float2* __restrict__ T, int n) {
    int i = blockIdx.x * blockDim.x + threadIdx.x;
    if (i >= n) return;
    float a = angles[i];
    float c = cosf(a), s = sinf(a);
    int l = i >> 11, aa = i & 2047;
    int region, jj, t, ii;
    if (l < 3)      { region = 0; jj = l;     t = aa >> 2;  ii = aa & 3; }
    else if (l < 6) { region = 1; jj = l - 3; int B = aa >> 5, r = aa & 31;
                      ii = r >> 3; t = 8 * B + (r & 7); }
    else if (l < 9) { region = 2; jj = l - 6; int S = aa >> 8, r = aa & 255;
                      ii = r >> 6; t = 64 * S + (r & 63); }
    else            { region = 3; jj = l - 9; ii = aa >> 9; t = aa & 511; }
    int f4 = region * 3072 + (jj * 2 + (ii >> 1)) * 512 + t;
    T[f4 * 2 + (ii & 1)] = make_float2(c, s);
}

// apply 3 layers (local strides 1,2,4) on packed w[8] with angle regs A[6]
#define PHASE_ROTS(A, w)                                                   \
    _Pragma("unroll")                                                      \
    for (int jj = 0; jj < 3; ++jj) {                                       \
        const int st = 1 << jj;                                            \
        _Pragma("unroll")                                                  \
        for (int m = 0; m < 8; ++m) {                                      \
            if (!(m & st)) {                                               \
                const int ii = inner_idx(m, jj);                           \
                const float c = (ii & 1) ? A[jj*2+(ii>>1)].z : A[jj*2+(ii>>1)].x; \
                const float s = (ii & 1) ? A[jj*2+(ii>>1)].w : A[jj*2+(ii>>1)].y; \
                rot2(w[m], w[m + st], c, s);                               \
            }                                                              \
        }                                                                  \
    }

__global__ void __launch_bounds__(BLOCK, 8)
butterfly_kernel(const float* __restrict__ x, const float4* __restrict__ T4,
                 float* __restrict__ out) {
    __shared__ v2f buf[DIM];                // 32 KiB interleaved {r0[e], r1[e]}
    const int t = threadIdx.x;
    const long row0 = (long)blockIdx.x * 2;

    v2f w[8];

    // ===== P1: e = 8t+k, layers 0-2; x loaded directly from global =====
    {
        const float* p0 = x + row0 * DIM + 8 * t;
        const float* p1 = p0 + DIM;
        float4 a = *(const float4*)(p0),     b = *(const float4*)(p0 + 4);
        float4 c = *(const float4*)(p1),     d = *(const float4*)(p1 + 4);
        w[0] = v2f{a.x, c.x}; w[1] = v2f{a.y, c.y};
        w[2] = v2f{a.z, c.z}; w[3] = v2f{a.w, c.w};
        w[4] = v2f{b.x, d.x}; w[5] = v2f{b.y, d.y};
        w[6] = v2f{b.z, d.z}; w[7] = v2f{b.w, d.w};
        float4 A[6];
        #pragma unroll
        for (int k = 0; k < 6; ++k) A[k] = T4[k * 512 + t];
        PHASE_ROTS(A, w)
        // b128 writes: units (2Q', 2Q'+1) = elements (e, e+1), Q' = swzQ(4t+q)
        #pragma unroll
        for (int q = 0; q < 4; ++q) {
            *(float4*)(&buf[2 * swzQ(4 * t + q)]) =
                make_float4(w[2*q].x, w[2*q].y, w[2*q+1].x, w[2*q+1].y);
        }
    }
    BAR();

    // ===== P2: e = 64(t>>3) + 8m + (t&7), layers 3-5 (b64) =====
    {
        const int eb = 64 * (t >> 3) + (t & 7);
        int ps[8];
        #pragma unroll
        for (int m = 0; m < 8; ++m) {
            ps[m] = uslot(eb + 8 * m);
            w[m] = buf[ps[m]];
        }
        float4 A[6];
        #pragma unroll
        for (int k = 0; k < 6; ++k) A[k] = T4[3072 + k * 512 + t];
        PHASE_ROTS(A, w)
        #pragma unroll
        for (int m = 0; m < 8; ++m) buf[ps[m]] = w[m];   // own slots
    }
    BAR();

    // ===== P3: e = 512(t>>6) + 64m + (t&63), layers 6-8 (b64) =====
    {
        const int eb = 512 * (t >> 6) + (t & 63);
        int ps[8];
        #pragma unroll
        for (int m = 0; m < 8; ++m) {
            ps[m] = uslot(eb + 64 * m);
            w[m] = buf[ps[m]];
        }
        float4 A[6];
        #pragma unroll
        for (int k = 0; k < 6; ++k) A[k] = T4[6144 + k * 512 + t];
        PHASE_ROTS(A, w)
        #pragma unroll
        for (int m = 0; m < 8; ++m) buf[ps[m]] = w[m];
    }
    BAR();

    // ===== P4: e = t + 512m, layers 9-11 (b64); store =====
    {
        #pragma unroll
        for (int m = 0; m < 8; ++m) w[m] = buf[uslot(t + 512 * m)];
        float4 A[6];
        #pragma unroll
        for (int k = 0; k < 6; ++k) A[k] = T4[9216 + k * 512 + t];
        PHASE_ROTS(A, w)
        float* o0 = out + row0 * DIM + t;
        float* o1 = o0 + DIM;
        #pragma unroll
        for (int m = 0; m < 8; ++m) {
            o0[m << 9] = w[m].x;
            o1[m << 9] = w[m].y;
        }
    }
}

extern "C" void kernel_launch(void* const* d_in, const int* in_sizes, int n_in,
                              void* d_out, int out_size, void* d_ws, size_t ws_size,
                              hipStream_t stream) {
    (void)in_sizes; (void)n_in; (void)out_size; (void)ws_size;
    const float* x      = (const float*)d_in[0];
    const float* angles = (const float*)d_in[1];
    float* out = (float*)d_out;

    const int n = LAYERS * NANG;                    // 24576 angles, 192 KiB table
    cs_kernel<<<(n + 255) / 256, 256, 0, stream>>>(angles, (float2*)d_ws, n);
    butterfly_kernel<<<BATCH / 2, BLOCK, 0, stream>>>(x, (const float4*)d_ws, out);
}

// Round 10
// 53.152 us; speedup vs baseline: 1.3624x; 1.1474x over previous
//
#include <hip/hip_runtime.h>
#include <hip/hip_fp16.h>

// ButterflyRotation: 12 butterfly layers over rows of 4096 fp32.
// R10: R9 skeleton (BLOCK=512, 2 rows packed as v2f, interleaved 32 KiB LDS,
// radix-8 x 4 phases, 3 lgkm-only barriers, grid 4096 dispatch-ordered) +
//  - packed-f16 angle table: u32 = {h(1-cos) | h(sin)<<16}, 96 KiB total
//    (halves angle bytes; per-block phase slice 24 KB fits L1)
//  - one-phase-ahead angle prefetch (ping-pong uint4 triples; loads fly
//    across barriers, compiler emits counted vmcnt before unpack)
//   P1: e = 8t+m                    -> layers 0-2
//   P2: e = 64(t>>3)+8m+(t&7)       -> layers 3-5
//   P3: e = 512(t>>6)+64m+(t&63)    -> layers 6-8
//   P4: e = t+512m                  -> layers 9-11

#define DIM    4096
#define LAYERS 12
#define BATCH  8192
#define NANG   2048
#define BLOCK  512

typedef unsigned int u32;
typedef float v2f __attribute__((ext_vector_type(2)));

// lgkm-only barrier: global loads stay in flight across it (rule #18 fence)
#define BAR() do {                                             \
    asm volatile("s_waitcnt lgkmcnt(0)" ::: "memory");         \
    __builtin_amdgcn_sched_barrier(0);                         \
    __builtin_amdgcn_s_barrier();                              \
} while (0)

// quad-level swizzle (involution: only bits 0-2 change)
__device__ __forceinline__ int swzQ(int Q) {
    return Q ^ ((Q >> 3) & 7) ^ ((Q >> 6) & 7);
}
// element -> interleaved 8B-unit slot (quad swizzle in packed space)
__device__ __forceinline__ int uslot(int e) {
    return 2 * swzQ(e >> 1) + (e & 1);
}
// butterfly sub-index for left element m at local level jj (stride 2^jj)
__device__ __forceinline__ constexpr int inner_idx(int m, int jj) {
    return ((m >> (jj + 1)) << jj) + (m & ((1 << jj) - 1));
}

// packed rotation on both rows at once (v_pk_fma_f32 candidates)
__device__ __forceinline__ void rot2(v2f& xl, v2f& xr, float c, float s) {
    v2f nl = c * xl + s * xr;
    v2f nr = c * xr - s * xl;
    xl = nl; xr = nr;
}

// f16-packed transposed table: 12 groups x 512 threads x uint4
// (u32 component a&3 of group (region*3 + (a>>2)) holds angle a = jj*4+ii
//  of that phase for thread t, packed {h(1-c) | h(s)<<16}). 96 KiB.
__global__ void __launch_bounds__(256) cs_kernel(const float* __restrict__ angles,
                                                 u32* __restrict__ TH, int n) {
    int i = blockIdx.x * blockDim.x + threadIdx.x;
    if (i >= n) return;
    float a = angles[i];
    float c = cosf(a), s = sinf(a);
    int l = i >> 11, aa = i & 2047;
    int region, jj, t, ii;
    if (l < 3)      { region = 0; jj = l;     t = aa >> 2;  ii = aa & 3; }
    else if (l < 6) { region = 1; jj = l - 3; int B = aa >> 5, r = aa & 31;
                      ii = r >> 3; t = 8 * B + (r & 7); }
    else if (l < 9) { region = 2; jj = l - 6; int S = aa >> 8, r = aa & 255;
                      ii = r >> 6; t = 64 * S + (r & 63); }
    else            { region = 3; jj = l - 9; ii = aa >> 9; t = aa & 511; }
    int a_idx = jj * 4 + ii;
    int flat = ((region * 3 + (a_idx >> 2)) * 512 + t) * 4 + (a_idx & 3);
    u32 lo = (u32)__half_as_ushort(__float2half(1.0f - c));
    u32 hi = (u32)__half_as_ushort(__float2half(s));
    TH[flat] = lo | (hi << 16);
}

// unpack 3 uint4 -> 12 (c,s) pairs; all indices compile-time after unroll
#define UNPACK_ANGLES(U0, U1, U2, ca, sa) do {                             \
    const u32 _u[12] = {U0.x, U0.y, U0.z, U0.w, U1.x, U1.y, U1.z, U1.w,    \
                        U2.x, U2.y, U2.z, U2.w};                           \
    _Pragma("unroll")                                                      \
    for (int a = 0; a < 12; ++a) {                                         \
        __half2 h2 = *reinterpret_cast<const __half2*>(&_u[a]);            \
        float2 f = __half22float2(h2);                                     \
        ca[a] = 1.0f - f.x;                                                \
        sa[a] = f.y;                                                       \
    }                                                                      \
} while (0)

// apply 3 layers (local strides 1,2,4) on packed w[8]
#define PHASE_ROTS(ca, sa, w)                                              \
    _Pragma("unroll")                                                      \
    for (int jj = 0; jj < 3; ++jj) {                                       \
        const int st = 1 << jj;                                            \
        _Pragma("unroll")                                                  \
        for (int m = 0; m < 8; ++m) {                                      \
            if (!(m & st)) {                                               \
                const int a = jj * 4 + inner_idx(m, jj);                   \
                rot2(w[m], w[m + st], ca[a], sa[a]);                       \
            }                                                              \
        }                                                                  \
    }

__global__ void __launch_bounds__(BLOCK, 6)
butterfly_kernel(const float* __restrict__ x, const uint4* __restrict__ TH4,
                 float* __restrict__ out) {
    __shared__ v2f buf[DIM];                // 32 KiB interleaved {r0[e], r1[e]}
    const int t = threadIdx.x;
    const long row0 = (long)blockIdx.x * 2;

    v2f w[8];
    float ca[12], sa[12];

    // ===== P1: e = 8t+k, layers 0-2; x direct from global =====
    {
        // current-phase angles + x data
        uint4 A0 = TH4[0 * 512 + t], A1 = TH4[1 * 512 + t], A2 = TH4[2 * 512 + t];
        const float* p0 = x + row0 * DIM + 8 * t;
        const float* p1 = p0 + DIM;
        float4 a = *(const float4*)(p0),     b = *(const float4*)(p0 + 4);
        float4 c = *(const float4*)(p1),     d = *(const float4*)(p1 + 4);
        // prefetch P2 angles (fly across BAR)
        uint4 B0 = TH4[3 * 512 + t], B1 = TH4[4 * 512 + t], B2 = TH4[5 * 512 + t];

        w[0] = v2f{a.x, c.x}; w[1] = v2f{a.y, c.y};
        w[2] = v2f{a.z, c.z}; w[3] = v2f{a.w, c.w};
        w[4] = v2f{b.x, d.x}; w[5] = v2f{b.y, d.y};
        w[6] = v2f{b.z, d.z}; w[7] = v2f{b.w, d.w};
        UNPACK_ANGLES(A0, A1, A2, ca, sa);
        PHASE_ROTS(ca, sa, w)
        // b128 writes: units (2Q', 2Q'+1), Q' = swzQ(4t+q)
        #pragma unroll
        for (int q = 0; q < 4; ++q) {
            *(float4*)(&buf[2 * swzQ(4 * t + q)]) =
                make_float4(w[2*q].x, w[2*q].y, w[2*q+1].x, w[2*q+1].y);
        }
        BAR();

        // ===== P2: e = 64(t>>3) + 8m + (t&7), layers 3-5 (b64) =====
        // prefetch P3 angles first (no wait), then consume B*
        uint4 C0 = TH4[6 * 512 + t], C1 = TH4[7 * 512 + t], C2 = TH4[8 * 512 + t];
        {
            const int eb = 64 * (t >> 3) + (t & 7);
            int ps[8];
            #pragma unroll
            for (int m = 0; m < 8; ++m) {
                ps[m] = uslot(eb + 8 * m);
                w[m] = buf[ps[m]];
            }
            UNPACK_ANGLES(B0, B1, B2, ca, sa);
            PHASE_ROTS(ca, sa, w)
            #pragma unroll
            for (int m = 0; m < 8; ++m) buf[ps[m]] = w[m];   // own slots
        }
        BAR();

        // ===== P3: e = 512(t>>6) + 64m + (t&63), layers 6-8 (b64) =====
        // prefetch P4 angles first, then consume C*
        uint4 D0 = TH4[9 * 512 + t], D1 = TH4[10 * 512 + t], D2 = TH4[11 * 512 + t];
        {
            const int eb = 512 * (t >> 6) + (t & 63);
            int ps[8];
            #pragma unroll
            for (int m = 0; m < 8; ++m) {
                ps[m] = uslot(eb + 64 * m);
                w[m] = buf[ps[m]];
            }
            UNPACK_ANGLES(C0, C1, C2, ca, sa);
            PHASE_ROTS(ca, sa, w)
            #pragma unroll
            for (int m = 0; m < 8; ++m) buf[ps[m]] = w[m];
        }
        BAR();

        // ===== P4: e = t + 512m, layers 9-11 (b64); store =====
        {
            #pragma unroll
            for (int m = 0; m < 8; ++m) w[m] = buf[uslot(t + 512 * m)];
            UNPACK_ANGLES(D0, D1, D2, ca, sa);
            PHASE_ROTS(ca, sa, w)
            float* o0 = out + row0 * DIM + t;
            float* o1 = o0 + DIM;
            #pragma unroll
            for (int m = 0; m < 8; ++m) {
                o0[m << 9] = w[m].x;
                o1[m << 9] = w[m].y;
            }
        }
    }
}

extern "C" void kernel_launch(void* const* d_in, const int* in_sizes, int n_in,
                              void* d_out, int out_size, void* d_ws, size_t ws_size,
                              hipStream_t stream) {
    (void)in_sizes; (void)n_in; (void)out_size; (void)ws_size;
    const float* x      = (const float*)d_in[0];
    const float* angles = (const float*)d_in[1];
    float* out = (float*)d_out;

    const int n = LAYERS * NANG;                    // 24576 angles, 96 KiB table
    cs_kernel<<<(n + 255) / 256, 256, 0, stream>>>(angles, (u32*)d_ws, n);
    butterfly_kernel<<<BATCH / 2, BLOCK, 0, stream>>>(x, (const uint4*)d_ws, out);
}